// Round 1
// baseline (460.226 us; speedup 1.0000x reference)
//
#include <hip/hip_runtime.h>
#include <math.h>

#define B 8
#define L 8192
#define H 1024
#define SCALE 0.03125f   // 1/sqrt(1024)

#define MAX_HIL 64
#define MAX_CAN 160
// ws layout (as int/float array):
//   ws_i[0] = n_hilbert, ws_i[1] = n_cantor
//   ws_i[2 .. 2+MAX_HIL)           : hilbert indices
//   ws_i[2+MAX_HIL .. 2+MAX_HIL+MAX_CAN) : cantor indices
//   float offset 256               : hil_out (B*H) then can_out (B*H)
//   float offset 256 + 2*B*H       : partials (KP*B*H)
#define IDX_WORDS 256

__device__ inline void d2xy_dev(int n, int d, int* px, int* py) {
    int x = 0, y = 0;
    for (int s = 1; s < n; s *= 2) {
        int rx = 1 & (d / 2);
        int ry = 1 & (d ^ rx);
        if (ry == 0) {
            if (rx == 1) { x = s - 1 - x; y = s - 1 - y; }
            int t = x; x = y; y = t;
        }
        x += s * rx; y += s * ry;
        d /= 4;
    }
    *px = x; *py = y;
}

__device__ inline int xy2d_dev(int n, int x, int y) {
    int d = 0;
    for (int s = n / 2; s > 0; s /= 2) {
        int rx = ((x & s) > 0) ? 1 : 0;
        int ry = ((y & s) > 0) ? 1 : 0;
        d += s * s * ((3 * rx) ^ ry);
        if (ry == 0) {
            if (rx == 1) { x = s - 1 - x; y = s - 1 - y; }
            int t = x; x = y; y = t;
        }
    }
    return d;
}

__global__ void build_indices_kernel(const int* __restrict__ qidx_p,
                                     int* __restrict__ ws_i) {
    __shared__ int cand[49];
    __shared__ int ccxy[2];
    int tid = threadIdx.x;

    if (tid == 0) {
        // order = ceil(log2(sqrt(10000))) = 7, grid = 128, n_coords = 10000
        int center = qidx_p[0];
        if (center > 9999) center = 9999;
        if (center < 0) center = 0;
        int cx, cy;
        d2xy_dev(128, center, &cx, &cy);
        ccxy[0] = cx; ccxy[1] = cy;
    }
    __syncthreads();

    if (tid < 49) {
        int dx = tid / 7 - 3, dy = tid % 7 - 3;
        int x = ccxy[0] + dx, y = ccxy[1] + dy;
        int val = -1;
        if (x >= 0 && x < 128 && y >= 0 && y < 128) {
            int i = xy2d_dev(128, x, y);
            if (i < L) val = i;
        }
        cand[tid] = val;
    }
    __syncthreads();

    if (tid == 0) {
        int nh = 0;
        for (int j = 0; j < 49; j++)
            if (cand[j] >= 0) ws_i[2 + nh++] = cand[j];
        ws_i[0] = nh;

        // Cantor: depth = min(int(log2(8192)), 7) = 7 -> 129 positions.
        // Double math exactly mirrors the numpy reference for exact truncation.
        double pos[130], tmp[130];
        pos[0] = 0.0; pos[1] = 1.0;
        int len = 2;
        for (int it = 0; it < 7; ++it) {
            int nl = 0;
            for (int i2 = 0; i2 < len - 1; i2++) {
                double l = pos[i2], r = pos[i2 + 1];
                double third = (r - l) / 3.0;
                tmp[nl++] = l;
                tmp[nl++] = l + third;
            }
            tmp[nl++] = pos[len - 1];
            for (int i2 = 0; i2 < nl; i2++) pos[i2] = tmp[i2];
            len = nl;
        }
        int nc = 0;
        long long prev = -1;
        for (int i2 = 0; i2 < len; i2++) {
            long long id = (long long)(pos[i2] * (double)(L - 1)); // trunc == floor (pos>=0)
            if (id != prev) { ws_i[2 + MAX_HIL + nc++] = (int)id; prev = id; }
        }
        ws_i[1] = nc;
    }
}

__global__ __launch_bounds__(256)
void sparse_attn_kernel(const float* __restrict__ q, const float* __restrict__ k,
                        const float* __restrict__ v, const int* __restrict__ ws_i,
                        float* __restrict__ outs) {
    int b   = blockIdx.x;
    int set = blockIdx.y;               // 0 = hilbert, 1 = cantor
    int n   = ws_i[set];
    const int* idx = ws_i + 2 + (set == 0 ? 0 : MAX_HIL);

    __shared__ float qs[H];
    __shared__ float probs[MAX_CAN];
    __shared__ float s_inv;

    int tid = threadIdx.x;
    for (int h = tid; h < H; h += 256) qs[h] = q[(size_t)b * H + h];
    __syncthreads();

    int wid = tid >> 6, lane = tid & 63;
    // wave-per-key dot products
    for (int j = wid; j < n; j += 4) {
        const float* krow = k + ((size_t)b * L + (size_t)idx[j]) * H;
        float p = 0.f;
        for (int h = lane; h < H; h += 64) p += qs[h] * krow[h];
        for (int off = 32; off; off >>= 1) p += __shfl_down(p, off);
        if (lane == 0) probs[j] = p * SCALE;
    }
    __syncthreads();

    // softmax on wave 0
    if (wid == 0) {
        float m = -1e30f;
        for (int j = lane; j < n; j += 64) m = fmaxf(m, probs[j]);
        for (int mask = 32; mask; mask >>= 1) m = fmaxf(m, __shfl_xor(m, mask));
        float s = 0.f;
        for (int j = lane; j < n; j += 64) {
            float e = expf(probs[j] - m);
            probs[j] = e;
            s += e;
        }
        for (int mask = 32; mask; mask >>= 1) s += __shfl_xor(s, mask);
        if (lane == 0) s_inv = 1.f / s;
    }
    __syncthreads();

    float inv = s_inv;
    float* outp = outs + ((size_t)set * B + b) * H;
    for (int h = tid; h < H; h += 256) {
        float acc = 0.f;
        for (int j = 0; j < n; j++)
            acc += probs[j] * v[((size_t)b * L + (size_t)idx[j]) * H + h];
        outp[h] = acc * inv;
    }
}

__global__ __launch_bounds__(256)
void colsum_partial_kernel(const float* __restrict__ v, float* __restrict__ partials,
                           int rows) {
    int kp = blockIdx.x;
    int b  = blockIdx.y;
    int t  = threadIdx.x;           // covers 4 floats (float4) -> all 1024 cols
    const float4* base =
        (const float4*)(v + ((size_t)b * L + (size_t)kp * rows) * H);
    float4 acc = make_float4(0.f, 0.f, 0.f, 0.f);
    for (int r = 0; r < rows; r++) {
        float4 x = base[(size_t)r * (H / 4) + t];
        acc.x += x.x; acc.y += x.y; acc.z += x.z; acc.w += x.w;
    }
    float4* o = (float4*)(partials + ((size_t)kp * B + b) * H);
    o[t] = acc;
}

__global__ __launch_bounds__(256)
void combine_kernel(const float* __restrict__ pw, const float* __restrict__ ws_f,
                    const float* __restrict__ partials, float* __restrict__ out,
                    int KP) {
    int i = blockIdx.x * 256 + threadIdx.x;   // 0 .. B*H
    if (i >= B * H) return;
    float w0 = pw[0], w1 = pw[1], w2 = pw[2];
    float m  = fmaxf(w0, fmaxf(w1, w2));
    float e0 = expf(w0 - m), e1 = expf(w1 - m), e2 = expf(w2 - m);
    float invs = 1.f / (e0 + e1 + e2);

    const float* hil = ws_f + IDX_WORDS;
    const float* can = hil + B * H;

    float s = 0.f;
    for (int kp = 0; kp < KP; kp++) s += partials[(size_t)kp * B * H + i];
    float mean = s * (1.0f / (float)L);   // dragon weights are exactly 0 -> uniform attn

    out[i] = (e0 * hil[i] + e1 * can[i] + e2 * mean) * invs;
}

extern "C" void kernel_launch(void* const* d_in, const int* in_sizes, int n_in,
                              void* d_out, int out_size, void* d_ws, size_t ws_size,
                              hipStream_t stream) {
    const float* q  = (const float*)d_in[0];
    const float* k  = (const float*)d_in[1];
    const float* v  = (const float*)d_in[2];
    const float* pw = (const float*)d_in[3];
    const int* qidx = (const int*)d_in[4];

    float* ws_f = (float*)d_ws;
    int*   ws_i = (int*)d_ws;
    float* outs     = ws_f + IDX_WORDS;
    float* partials = ws_f + IDX_WORDS + 2 * B * H;

    int KP = 128;
    while (KP > 8 &&
           (size_t)(IDX_WORDS + 2 * B * H + (size_t)KP * B * H) * 4 > ws_size)
        KP >>= 1;
    int rows = L / KP;

    build_indices_kernel<<<1, 64, 0, stream>>>(qidx, ws_i);
    sparse_attn_kernel<<<dim3(B, 2), 256, 0, stream>>>(q, k, v, ws_i, outs);
    colsum_partial_kernel<<<dim3(KP, B), 256, 0, stream>>>(v, partials, rows);
    combine_kernel<<<(B * H + 255) / 256, 256, 0, stream>>>(pw, ws_f, partials,
                                                            (float*)d_out, KP);
}

// Round 2
// 219.100 us; speedup vs baseline: 2.1005x; 2.1005x over previous
//
#include <hip/hip_runtime.h>
#include <math.h>

#define B 8
#define L 8192
#define H 1024
#define SCALE 0.03125f   // 1/sqrt(1024)

#define MAX_HIL 64
#define MAX_CAN 160
#define MAX_N   256      // padded per-(set,b) score stride

// ws layout (floats/ints):
//   [0..2)                 n_hilbert, n_cantor
//   [2..2+MAX_HIL)         hilbert indices
//   [2+MAX_HIL..)          cantor indices
//   OFF_OUTS  (256)        hil_out (B*H) then can_out (B*H)
//   OFF_SCORES             scores  (2*B*MAX_N)
//   OFF_PROBS              probs   (2*B*MAX_N)
//   OFF_PART               partials (KP*B*H)
#define OFF_OUTS   256
#define OFF_SCORES (OFF_OUTS + 2 * B * H)
#define OFF_PROBS  (OFF_SCORES + 2 * B * MAX_N)
#define OFF_PART   (OFF_PROBS + 2 * B * MAX_N)

__device__ inline void d2xy_dev(int n, int d, int* px, int* py) {
    int x = 0, y = 0;
    for (int s = 1; s < n; s *= 2) {
        int rx = 1 & (d / 2);
        int ry = 1 & (d ^ rx);
        if (ry == 0) {
            if (rx == 1) { x = s - 1 - x; y = s - 1 - y; }
            int t = x; x = y; y = t;
        }
        x += s * rx; y += s * ry;
        d /= 4;
    }
    *px = x; *py = y;
}

__device__ inline int xy2d_dev(int n, int x, int y) {
    int d = 0;
    for (int s = n / 2; s > 0; s /= 2) {
        int rx = ((x & s) > 0) ? 1 : 0;
        int ry = ((y & s) > 0) ? 1 : 0;
        d += s * s * ((3 * rx) ^ ry);
        if (ry == 0) {
            if (rx == 1) { x = s - 1 - x; y = s - 1 - y; }
            int t = x; x = y; y = t;
        }
    }
    return d;
}

__global__ void build_indices_kernel(const int* __restrict__ qidx_p,
                                     int* __restrict__ ws_i) {
    __shared__ int cand[49];
    __shared__ int ccxy[2];
    int tid = threadIdx.x;

    if (tid == 0) {
        int center = qidx_p[0];
        if (center > 9999) center = 9999;
        if (center < 0) center = 0;
        int cx, cy;
        d2xy_dev(128, center, &cx, &cy);
        ccxy[0] = cx; ccxy[1] = cy;
    }
    __syncthreads();

    if (tid < 49) {
        int dx = tid / 7 - 3, dy = tid % 7 - 3;
        int x = ccxy[0] + dx, y = ccxy[1] + dy;
        int val = -1;
        if (x >= 0 && x < 128 && y >= 0 && y < 128) {
            int i = xy2d_dev(128, x, y);
            if (i < L) val = i;
        }
        cand[tid] = val;
    }
    __syncthreads();

    if (tid == 0) {
        int nh = 0;
        for (int j = 0; j < 49; j++)
            if (cand[j] >= 0) ws_i[2 + nh++] = cand[j];
        ws_i[0] = nh;

        // Cantor depth 7 -> 129 positions; double math matches numpy exactly.
        double pos[130], tmp[130];
        pos[0] = 0.0; pos[1] = 1.0;
        int len = 2;
        for (int it = 0; it < 7; ++it) {
            int nl = 0;
            for (int i2 = 0; i2 < len - 1; i2++) {
                double l = pos[i2], r = pos[i2 + 1];
                double third = (r - l) / 3.0;
                tmp[nl++] = l;
                tmp[nl++] = l + third;
            }
            tmp[nl++] = pos[len - 1];
            for (int i2 = 0; i2 < nl; i2++) pos[i2] = tmp[i2];
            len = nl;
        }
        int nc = 0;
        long long prev = -1;
        for (int i2 = 0; i2 < len; i2++) {
            long long id = (long long)(pos[i2] * (double)(L - 1));
            if (id != prev) { ws_i[2 + MAX_HIL + nc++] = (int)id; prev = id; }
        }
        ws_i[1] = nc;
    }
}

// grid (B, 2, 45): wave w computes score for key j = z*4 + w
__global__ __launch_bounds__(256)
void scores_kernel(const float* __restrict__ q, const float* __restrict__ k,
                   const int* __restrict__ ws_i, float* __restrict__ ws_f) {
    int b   = blockIdx.x;
    int set = blockIdx.y;
    int n   = ws_i[set];
    int wid  = threadIdx.x >> 6, lane = threadIdx.x & 63;
    int j = blockIdx.z * 4 + wid;
    if (j >= n) return;

    const int* idx = ws_i + 2 + (set == 0 ? 0 : MAX_HIL);
    const float* qrow = q + (size_t)b * H;
    const float* krow = k + ((size_t)b * L + (size_t)idx[j]) * H;

    float p = 0.f;
    #pragma unroll
    for (int i = 0; i < H / 64; i++) {
        int h = lane + i * 64;
        p += qrow[h] * krow[h];
    }
    #pragma unroll
    for (int off = 32; off; off >>= 1) p += __shfl_down(p, off);
    if (lane == 0)
        ws_f[OFF_SCORES + ((size_t)set * B + b) * MAX_N + j] = p * SCALE;
}

// grid (B, 2), 64 threads: normalized softmax probs
__global__ __launch_bounds__(64)
void softmax_kernel(const int* __restrict__ ws_i, float* __restrict__ ws_f) {
    int b = blockIdx.x, set = blockIdx.y;
    int n = ws_i[set];
    int lane = threadIdx.x;
    const float* sc = ws_f + OFF_SCORES + ((size_t)set * B + b) * MAX_N;
    float* pr       = ws_f + OFF_PROBS  + ((size_t)set * B + b) * MAX_N;

    float m = -1e30f;
    for (int j = lane; j < n; j += 64) m = fmaxf(m, sc[j]);
    #pragma unroll
    for (int mask = 32; mask; mask >>= 1) m = fmaxf(m, __shfl_xor(m, mask));
    float s = 0.f;
    for (int j = lane; j < n; j += 64) s += expf(sc[j] - m);
    #pragma unroll
    for (int mask = 32; mask; mask >>= 1) s += __shfl_xor(s, mask);
    float inv = 1.f / s;
    for (int j = lane; j < n; j += 64) pr[j] = expf(sc[j] - m) * inv;
}

// grid (B, 2, 16): block owns cols [z*64, z*64+64); 4 waves split keys, LDS-reduce
__global__ __launch_bounds__(256)
void pv_kernel(const float* __restrict__ v, const int* __restrict__ ws_i,
               float* __restrict__ ws_f) {
    int b   = blockIdx.x;
    int set = blockIdx.y;
    int c0  = blockIdx.z * 64;
    int n   = ws_i[set];
    const int* idx = ws_i + 2 + (set == 0 ? 0 : MAX_HIL);
    const float* pr = ws_f + OFF_PROBS + ((size_t)set * B + b) * MAX_N;

    int lane = threadIdx.x & 63, sub = threadIdx.x >> 6;
    float acc = 0.f;
    for (int j = sub; j < n; j += 4)
        acc += pr[j] * v[((size_t)b * L + (size_t)idx[j]) * H + c0 + lane];

    __shared__ float red[4][64];
    red[sub][lane] = acc;
    __syncthreads();
    if (sub == 0) {
        float r = red[0][lane] + red[1][lane] + red[2][lane] + red[3][lane];
        ws_f[OFF_OUTS + ((size_t)set * B + b) * H + c0 + lane] = r;
    }
}

__global__ __launch_bounds__(256)
void colsum_partial_kernel(const float* __restrict__ v, float* __restrict__ partials,
                           int rows) {
    int kp = blockIdx.x;
    int b  = blockIdx.y;
    int t  = threadIdx.x;
    const float4* base =
        (const float4*)(v + ((size_t)b * L + (size_t)kp * rows) * H);
    float4 acc = make_float4(0.f, 0.f, 0.f, 0.f);
    for (int r = 0; r < rows; r++) {
        float4 x = base[(size_t)r * (H / 4) + t];
        acc.x += x.x; acc.y += x.y; acc.z += x.z; acc.w += x.w;
    }
    float4* o = (float4*)(partials + ((size_t)kp * B + b) * H);
    o[t] = acc;
}

__global__ __launch_bounds__(256)
void combine_kernel(const float* __restrict__ pw, const float* __restrict__ ws_f,
                    const float* __restrict__ partials, float* __restrict__ out,
                    int KP) {
    int i = blockIdx.x * 256 + threadIdx.x;
    if (i >= B * H) return;
    float w0 = pw[0], w1 = pw[1], w2 = pw[2];
    float m  = fmaxf(w0, fmaxf(w1, w2));
    float e0 = expf(w0 - m), e1 = expf(w1 - m), e2 = expf(w2 - m);
    float invs = 1.f / (e0 + e1 + e2);

    const float* hil = ws_f + OFF_OUTS;
    const float* can = hil + B * H;

    float s = 0.f;
    for (int kp = 0; kp < KP; kp++) s += partials[(size_t)kp * B * H + i];
    float mean = s * (1.0f / (float)L);   // dragon weights are exactly 0 -> uniform attn

    out[i] = (e0 * hil[i] + e1 * can[i] + e2 * mean) * invs;
}

extern "C" void kernel_launch(void* const* d_in, const int* in_sizes, int n_in,
                              void* d_out, int out_size, void* d_ws, size_t ws_size,
                              hipStream_t stream) {
    const float* q  = (const float*)d_in[0];
    const float* k  = (const float*)d_in[1];
    const float* v  = (const float*)d_in[2];
    const float* pw = (const float*)d_in[3];
    const int* qidx = (const int*)d_in[4];

    float* ws_f = (float*)d_ws;
    int*   ws_i = (int*)d_ws;
    float* partials = ws_f + OFF_PART;

    int KP = 128;
    while (KP > 8 && (size_t)(OFF_PART + (size_t)KP * B * H) * 4 > ws_size)
        KP >>= 1;
    int rows = L / KP;

    build_indices_kernel<<<1, 64, 0, stream>>>(qidx, ws_i);
    scores_kernel<<<dim3(B, 2, 45), 256, 0, stream>>>(q, k, ws_i, ws_f);
    softmax_kernel<<<dim3(B, 2), 64, 0, stream>>>(ws_i, ws_f);
    pv_kernel<<<dim3(B, 2, 16), 256, 0, stream>>>(v, ws_i, ws_f);
    colsum_partial_kernel<<<dim3(KP, B), 256, 0, stream>>>(v, partials, rows);
    combine_kernel<<<(B * H + 255) / 256, 256, 0, stream>>>(pw, ws_f, partials,
                                                            (float*)d_out, KP);
}

// Round 3
// 103.053 us; speedup vs baseline: 4.4659x; 2.1261x over previous
//
#include <hip/hip_runtime.h>
#include <math.h>

#define B 8
#define L 8192
#define H 1024
#define SCALE 0.03125f   // 1/sqrt(1024)

#define MAX_HIL 64
#define MAX_CAN 160
#define MAX_N   256      // padded per-(set,b) score stride

// ws layout (floats/ints):
//   [0..2)                 n_hilbert, n_cantor
//   [2..2+MAX_HIL)         hilbert indices
//   [2+MAX_HIL..)          cantor indices
//   OFF_OUTS  (256)        hil_out (B*H) then can_out (B*H)
//   OFF_SCORES             scores  (2*B*MAX_N)
//   OFF_PART               partials (KP*B*H)
#define OFF_OUTS   256
#define OFF_SCORES (OFF_OUTS + 2 * B * H)
#define OFF_PART   (OFF_SCORES + 2 * B * MAX_N)

__device__ inline void d2xy_dev(int n, int d, int* px, int* py) {
    int x = 0, y = 0;
    for (int s = 1; s < n; s *= 2) {
        int rx = 1 & (d / 2);
        int ry = 1 & (d ^ rx);
        if (ry == 0) {
            if (rx == 1) { x = s - 1 - x; y = s - 1 - y; }
            int t = x; x = y; y = t;
        }
        x += s * rx; y += s * ry;
        d /= 4;
    }
    *px = x; *py = y;
}

__device__ inline int xy2d_dev(int n, int x, int y) {
    int d = 0;
    for (int s = n / 2; s > 0; s /= 2) {
        int rx = ((x & s) > 0) ? 1 : 0;
        int ry = ((y & s) > 0) ? 1 : 0;
        d += s * s * ((3 * rx) ^ ry);
        if (ry == 0) {
            if (rx == 1) { x = s - 1 - x; y = s - 1 - y; }
            int t = x; x = y; y = t;
        }
    }
    return d;
}

__global__ void build_indices_kernel(const int* __restrict__ qidx_p,
                                     int* __restrict__ ws_i) {
    __shared__ int cand[49];
    int tid = threadIdx.x;

    // ---- Cantor: closed-form per-lane, registers only ----
    // Position tid<128: walk the 7-bit path MSB->LSB; tid==128: 1.0.
    if (tid < 129) {
        double l = (tid == 128) ? 1.0 : 0.0;
        if (tid < 128) {
            double gap = 1.0;
            #pragma unroll
            for (int bit = 6; bit >= 0; --bit) {
                double third = gap / 3.0;
                if ((tid >> bit) & 1) { l += third; gap -= third; }
                else                  { gap = third; }
            }
        }
        ws_i[2 + MAX_HIL + tid] = (int)(l * (double)(L - 1));
    }

    // ---- Hilbert: each candidate thread computes center + its own cell ----
    if (tid < 49) {
        int center = qidx_p[0];
        if (center > 9999) center = 9999;
        if (center < 0) center = 0;
        int cx, cy;
        d2xy_dev(128, center, &cx, &cy);
        int dx = tid / 7 - 3, dy = tid % 7 - 3;
        int x = cx + dx, y = cy + dy;
        int val = -1;
        if (x >= 0 && x < 128 && y >= 0 && y < 128) {
            int i = xy2d_dev(128, x, y);
            if (i < L) val = i;
        }
        cand[tid] = val;
    }
    __syncthreads();

    if (tid == 0) {
        int nh = 0;
        for (int j = 0; j < 49; j++)
            if (cand[j] >= 0) ws_i[2 + nh++] = cand[j];
        ws_i[0] = nh;
        ws_i[1] = 129;
    }
}

// grid (B, 2, 45): wave w computes score for key j = z*4 + w
__global__ __launch_bounds__(256)
void scores_kernel(const float* __restrict__ q, const float* __restrict__ k,
                   const int* __restrict__ ws_i, float* __restrict__ ws_f) {
    int b   = blockIdx.x;
    int set = blockIdx.y;
    int n   = ws_i[set];
    int wid = threadIdx.x >> 6, lane = threadIdx.x & 63;
    int j = blockIdx.z * 4 + wid;
    if (j >= n) return;

    const int* idx = ws_i + 2 + (set == 0 ? 0 : MAX_HIL);
    const float4* q4 = (const float4*)(q + (size_t)b * H);
    const float4* k4 = (const float4*)(k + ((size_t)b * L + (size_t)idx[j]) * H);

    float p = 0.f;
    #pragma unroll
    for (int i = 0; i < H / 256; i++) {
        float4 a = q4[lane + i * 64];
        float4 c = k4[lane + i * 64];
        p += a.x * c.x + a.y * c.y + a.z * c.z + a.w * c.w;
    }
    #pragma unroll
    for (int off = 32; off; off >>= 1) p += __shfl_down(p, off);
    if (lane == 0)
        ws_f[OFF_SCORES + ((size_t)set * B + b) * MAX_N + j] = p * SCALE;
}

// grid (B, 2, 16): block owns cols [z*64, z*64+64); softmax inline on wave 0,
// then 4 waves split keys, LDS-reduce.
__global__ __launch_bounds__(256)
void pv_kernel(const float* __restrict__ v, const int* __restrict__ ws_i,
               float* __restrict__ ws_f) {
    int b   = blockIdx.x;
    int set = blockIdx.y;
    int c0  = blockIdx.z * 64;
    int n   = ws_i[set];
    const int* idx = ws_i + 2 + (set == 0 ? 0 : MAX_HIL);
    const float* sc = ws_f + OFF_SCORES + ((size_t)set * B + b) * MAX_N;

    __shared__ float probs[MAX_N];
    __shared__ float red[4][64];
    __shared__ float sinv_sh;

    int tid = threadIdx.x, lane = tid & 63, sub = tid >> 6;
    if (sub == 0) {
        float m = -1e30f;
        for (int j = lane; j < n; j += 64) m = fmaxf(m, sc[j]);
        #pragma unroll
        for (int mask = 32; mask; mask >>= 1) m = fmaxf(m, __shfl_xor(m, mask));
        float s = 0.f;
        for (int j = lane; j < n; j += 64) {
            float e = expf(sc[j] - m);
            probs[j] = e;
            s += e;
        }
        #pragma unroll
        for (int mask = 32; mask; mask >>= 1) s += __shfl_xor(s, mask);
        if (lane == 0) sinv_sh = 1.f / s;
    }
    __syncthreads();

    float acc = 0.f;
    for (int j = sub; j < n; j += 4)
        acc += probs[j] * v[((size_t)b * L + (size_t)idx[j]) * H + c0 + lane];

    red[sub][lane] = acc;
    __syncthreads();
    if (sub == 0) {
        float r = (red[0][lane] + red[1][lane] + red[2][lane] + red[3][lane]) * sinv_sh;
        ws_f[OFF_OUTS + ((size_t)set * B + b) * H + c0 + lane] = r;
    }
}

__global__ __launch_bounds__(256)
void colsum_partial_kernel(const float* __restrict__ v, float* __restrict__ partials,
                           int rows) {
    int kp = blockIdx.x;
    int b  = blockIdx.y;
    int t  = threadIdx.x;
    const float4* base =
        (const float4*)(v + ((size_t)b * L + (size_t)kp * rows) * H);
    float4 acc = make_float4(0.f, 0.f, 0.f, 0.f);
    for (int r = 0; r < rows; r++) {
        float4 x = base[(size_t)r * (H / 4) + t];
        acc.x += x.x; acc.y += x.y; acc.z += x.z; acc.w += x.w;
    }
    float4* o = (float4*)(partials + ((size_t)kp * B + b) * H);
    o[t] = acc;
}

__global__ __launch_bounds__(256)
void combine_kernel(const float* __restrict__ pw, const float* __restrict__ ws_f,
                    const float* __restrict__ partials, float* __restrict__ out,
                    int KP) {
    int i = blockIdx.x * 256 + threadIdx.x;
    if (i >= B * H) return;
    float w0 = pw[0], w1 = pw[1], w2 = pw[2];
    float m  = fmaxf(w0, fmaxf(w1, w2));
    float e0 = expf(w0 - m), e1 = expf(w1 - m), e2 = expf(w2 - m);
    float invs = 1.f / (e0 + e1 + e2);

    const float* hil = ws_f + OFF_OUTS;
    const float* can = hil + B * H;

    float s = 0.f;
    for (int kp = 0; kp < KP; kp++) s += partials[(size_t)kp * B * H + i];
    float mean = s * (1.0f / (float)L);   // dragon weights are exactly 0 -> uniform attn

    out[i] = (e0 * hil[i] + e1 * can[i] + e2 * mean) * invs;
}

extern "C" void kernel_launch(void* const* d_in, const int* in_sizes, int n_in,
                              void* d_out, int out_size, void* d_ws, size_t ws_size,
                              hipStream_t stream) {
    const float* q  = (const float*)d_in[0];
    const float* k  = (const float*)d_in[1];
    const float* v  = (const float*)d_in[2];
    const float* pw = (const float*)d_in[3];
    const int* qidx = (const int*)d_in[4];

    float* ws_f = (float*)d_ws;
    int*   ws_i = (int*)d_ws;
    float* partials = ws_f + OFF_PART;

    int KP = 128;
    while (KP > 8 && (size_t)(OFF_PART + (size_t)KP * B * H) * 4 > ws_size)
        KP >>= 1;
    int rows = L / KP;

    build_indices_kernel<<<1, 256, 0, stream>>>(qidx, ws_i);
    scores_kernel<<<dim3(B, 2, 45), 256, 0, stream>>>(q, k, ws_i, ws_f);
    pv_kernel<<<dim3(B, 2, 16), 256, 0, stream>>>(v, ws_i, ws_f);
    colsum_partial_kernel<<<dim3(KP, B), 256, 0, stream>>>(v, partials, rows);
    combine_kernel<<<(B * H + 255) / 256, 256, 0, stream>>>(pw, ws_f, partials,
                                                            (float*)d_out, KP);
}

// Round 4
// 62.010 us; speedup vs baseline: 7.4218x; 1.6619x over previous
//
#include <hip/hip_runtime.h>
#include <math.h>

#define B 8
#define L 8192
#define H 1024
#define SCALE 0.03125f   // 1/sqrt(1024)

#define MAX_N 160        // >= 129 cantor keys
#define KP    128        // colsum partitions per batch (rows = 64)
#define ROWS  (L / KP)

// ws layout (floats):
//   OFF_OUTS (0)      hil_out (B*H) then can_out (B*H)
//   OFF_PART          partials (KP*B*H)
#define OFF_OUTS 0
#define OFF_PART (OFF_OUTS + 2 * B * H)

__device__ inline void d2xy_dev(int n, int d, int* px, int* py) {
    int x = 0, y = 0;
    for (int s = 1; s < n; s *= 2) {
        int rx = 1 & (d / 2);
        int ry = 1 & (d ^ rx);
        if (ry == 0) {
            if (rx == 1) { x = s - 1 - x; y = s - 1 - y; }
            int t = x; x = y; y = t;
        }
        x += s * rx; y += s * ry;
        d /= 4;
    }
    *px = x; *py = y;
}

__device__ inline int xy2d_dev(int n, int x, int y) {
    int d = 0;
    for (int s = n / 2; s > 0; s /= 2) {
        int rx = ((x & s) > 0) ? 1 : 0;
        int ry = ((y & s) > 0) ? 1 : 0;
        d += s * s * ((3 * rx) ^ ry);
        if (ry == 0) {
            if (rx == 1) { x = s - 1 - x; y = s - 1 - y; }
            int t = x; x = y; y = t;
        }
    }
    return d;
}

// Blocks 0..15: fused sparse attention (set = bid>>3, b = bid&7).
// Blocks 16..16+KP*B-1: colsum partial over a 64-row slice of v.
__global__ __launch_bounds__(1024)
void mega_kernel(const float* __restrict__ q, const float* __restrict__ k,
                 const float* __restrict__ v, const int* __restrict__ qidx_p,
                 float* __restrict__ ws_f) {
    int bid = blockIdx.x;
    int tid = threadIdx.x;

    if (bid < 16) {
        // ---------------- fused sparse attention ----------------
        int set = bid >> 3;   // 0 = hilbert, 1 = cantor
        int b   = bid & 7;

        __shared__ float qs[H];
        __shared__ float sc[MAX_N];
        __shared__ float probs[MAX_N];
        __shared__ int   idx[MAX_N];
        __shared__ int   n_sh;
        __shared__ float sinv_sh;

        // stage q row (4 KB)
        if (tid < H / 4)
            ((float4*)qs)[tid] = ((const float4*)(q + (size_t)b * H))[tid];

        // ---- per-block index derivation (registers + one wave) ----
        if (set == 1) {
            // Cantor: closed-form per-lane. Position tid<128 walks its 7-bit
            // path MSB->LSB; tid==128 is 1.0. Indices m/3^7*8191 are never
            // within 4.6e-4 of an integer -> truncation exact; all distinct.
            if (tid < 129) {
                double l = (tid == 128) ? 1.0 : 0.0;
                if (tid < 128) {
                    double gap = 1.0;
                    #pragma unroll
                    for (int bit = 6; bit >= 0; --bit) {
                        double third = gap / 3.0;
                        if ((tid >> bit) & 1) { l += third; gap -= third; }
                        else                  { gap = third; }
                    }
                }
                idx[tid] = (int)(l * (double)(L - 1));
            }
            if (tid == 0) n_sh = 129;
        } else {
            // Hilbert: 49 candidates in wave 0, ballot-compact (set order is
            // irrelevant: softmax+sum is permutation-invariant).
            if (tid < 64) {
                int center = qidx_p[0];
                if (center > 9999) center = 9999;
                if (center < 0) center = 0;
                int cx, cy;
                d2xy_dev(128, center, &cx, &cy);
                int val = -1;
                if (tid < 49) {
                    int x = cx + tid / 7 - 3, y = cy + tid % 7 - 3;
                    if (x >= 0 && x < 128 && y >= 0 && y < 128) {
                        int i = xy2d_dev(128, x, y);
                        if (i < L) val = i;
                    }
                }
                unsigned long long ball = __ballot(val >= 0);
                int pos = __popcll(ball & ((1ull << tid) - 1));
                if (val >= 0) idx[pos] = val;
                if (tid == 0) n_sh = __popcll(ball);
            }
        }
        __syncthreads();
        int n = n_sh;

        // ---- scores: wave per key ----
        int wid = tid >> 6, lane = tid & 63;
        for (int j = wid; j < n; j += 16) {
            const float4* k4 =
                (const float4*)(k + ((size_t)b * L + (size_t)idx[j]) * H);
            float p = 0.f;
            #pragma unroll
            for (int i = 0; i < H / 256; i++) {
                float4 a = ((float4*)qs)[lane + i * 64];
                float4 c = k4[lane + i * 64];
                p += a.x * c.x + a.y * c.y + a.z * c.z + a.w * c.w;
            }
            #pragma unroll
            for (int off = 32; off; off >>= 1) p += __shfl_down(p, off);
            if (lane == 0) sc[j] = p * SCALE;
        }
        __syncthreads();

        // ---- softmax on wave 0 ----
        if (wid == 0) {
            float m = -1e30f;
            for (int j = lane; j < n; j += 64) m = fmaxf(m, sc[j]);
            #pragma unroll
            for (int mask = 32; mask; mask >>= 1) m = fmaxf(m, __shfl_xor(m, mask));
            float s = 0.f;
            for (int j = lane; j < n; j += 64) {
                float e = expf(sc[j] - m);
                probs[j] = e;
                s += e;
            }
            #pragma unroll
            for (int mask = 32; mask; mask >>= 1) s += __shfl_xor(s, mask);
            if (lane == 0) sinv_sh = 1.f / s;
        }
        __syncthreads();

        // ---- PV: thread t owns column t ----
        float acc = 0.f;
        float sinv = sinv_sh;
        #pragma unroll 4
        for (int j = 0; j < n; j++)
            acc += probs[j] * v[((size_t)b * L + (size_t)idx[j]) * H + tid];
        ws_f[OFF_OUTS + ((size_t)set * B + b) * H + tid] = acc * sinv;

    } else {
        // ---------------- colsum partial (dragon mean) ----------------
        int cb = bid - 16;
        int kp = cb >> 3, b = cb & 7;
        int c  = tid & 255;      // float4 column
        int r4 = tid >> 8;       // row group 0..3

        const float4* base =
            (const float4*)(v + ((size_t)b * L + (size_t)kp * ROWS) * H);
        float4 acc = make_float4(0.f, 0.f, 0.f, 0.f);
        for (int rr = r4; rr < ROWS; rr += 4) {
            float4 x = base[(size_t)rr * (H / 4) + c];
            acc.x += x.x; acc.y += x.y; acc.z += x.z; acc.w += x.w;
        }

        __shared__ float4 red[4][256];
        red[r4][c] = acc;
        __syncthreads();
        if (r4 == 0) {
            float4 a0 = red[0][c], a1 = red[1][c], a2 = red[2][c], a3 = red[3][c];
            float4 s = make_float4(a0.x + a1.x + a2.x + a3.x,
                                   a0.y + a1.y + a2.y + a3.y,
                                   a0.z + a1.z + a2.z + a3.z,
                                   a0.w + a1.w + a2.w + a3.w);
            ((float4*)(ws_f + OFF_PART + ((size_t)kp * B + b) * H))[c] = s;
        }
    }
}

__global__ __launch_bounds__(256)
void combine_kernel(const float* __restrict__ pw, const float* __restrict__ ws_f,
                    float* __restrict__ out) {
    int i = blockIdx.x * 256 + threadIdx.x;
    if (i >= B * H) return;
    float w0 = pw[0], w1 = pw[1], w2 = pw[2];
    float m  = fmaxf(w0, fmaxf(w1, w2));
    float e0 = expf(w0 - m), e1 = expf(w1 - m), e2 = expf(w2 - m);
    float invs = 1.f / (e0 + e1 + e2);

    const float* hil = ws_f + OFF_OUTS;
    const float* can = hil + B * H;
    const float* partials = ws_f + OFF_PART;

    float s = 0.f;
    #pragma unroll 8
    for (int kp = 0; kp < KP; kp++) s += partials[(size_t)kp * B * H + i];
    float mean = s * (1.0f / (float)L);   // dragon weights are exactly 0 -> uniform attn

    out[i] = (e0 * hil[i] + e1 * can[i] + e2 * mean) * invs;
}

extern "C" void kernel_launch(void* const* d_in, const int* in_sizes, int n_in,
                              void* d_out, int out_size, void* d_ws, size_t ws_size,
                              hipStream_t stream) {
    const float* q  = (const float*)d_in[0];
    const float* k  = (const float*)d_in[1];
    const float* v  = (const float*)d_in[2];
    const float* pw = (const float*)d_in[3];
    const int* qidx = (const int*)d_in[4];

    float* ws_f = (float*)d_ws;

    mega_kernel<<<16 + KP * B, 1024, 0, stream>>>(q, k, v, qidx, ws_f);
    combine_kernel<<<(B * H + 255) / 256, 256, 0, stream>>>(pw, ws_f,
                                                            (float*)d_out);
}